// Round 5
// baseline (1648.491 us; speedup 1.0000x reference)
//
#include <hip/hip_runtime.h>
#include <math.h>

// PQLayer forward, MI355X — R5: bisection round (K1' x3 + K2 x2).
//   x:     (B, 512) fp32      d_in[0]
//   C:     (64, 256, 8) fp32  d_in[1]
//   out0:  x_hat (B, 512) fp32     = C[m, k*, :]
//   out1:  codes (B, 64, 256) fp32 = one_hot(k*)
//
// Measurement model: dur_us = ~707us poison-fill tax + kernel time. R2-R4
// addressable ~500us, insensitive to writer structure => K1 suspected pig
// (~300us vs 61us VALU floor). This round: dur = F + 3*t1' + 2*t2 bisects.
//   band ~1560 => K1 VALU-stall, packing partial     band ~1310 => K1 fixed
//   band ~1700 => K2 pig                             band ~1450 => fill-tax wrong
//
// K1' packs the np-exact dot tree into v_pk_{mul,add}_f32 via float2 ext
// vectors. Pairing keeps bit-exactness: S01=(x0,x1)*(c0,c1) rounds each half
// separately (same as scalar); T01=S01+S45=(t0,t1); then u0=t0+t1, u1=t2+t3,
// dot=u0+u1 are scalar adds in np's exact order.

#define B_SZ   16384
#define FEAT   512
#define M_SZ   64
#define K_SZ   256
#define D_SZ   8

typedef float v2f __attribute__((ext_vector_type(2)));

// ---------------- K1': packed argmax ----------------
// 4096 blocks x 256 threads; block = (m, chunk of 256 b), thread = one b.
__global__ __launch_bounds__(256) void pq_argmax(
    const float* __restrict__ x,
    const float* __restrict__ C,
    unsigned char* __restrict__ bestk8)   // [B][M]
{
#pragma clang fp contract(off)   // np einsum: separate product roundings, no FMA

    const int m     = blockIdx.x & (M_SZ - 1);   // block-uniform
    const int chunk = blockIdx.x >> 6;
    const int b     = (chunk << 8) | threadIdx.x;

    const float* xp = x + (size_t)b * FEAT + m * D_SZ;
    const float4 xa = ((const float4*)xp)[0];
    const float4 xb = ((const float4*)xp)[1];
    const v2f x01 = {xa.x, xa.y};
    const v2f x23 = {xa.z, xa.w};
    const v2f x45 = {xb.x, xb.y};
    const v2f x67 = {xb.z, xb.w};

    const float* __restrict__ Cm = C + (size_t)m * (K_SZ * D_SZ);

    float best  = -INFINITY;
    int   bestk = 0;

#pragma unroll 8
    for (int k = 0; k < K_SZ; ++k) {
        const v2f* cr = (const v2f*)(Cm + k * D_SZ);  // uniform -> s_load path
        v2f S01 = x01 * cr[0];        // v_pk_mul_f32: halves round separately
        v2f S23 = x23 * cr[1];
        v2f S45 = x45 * cr[2];
        v2f S67 = x67 * cr[3];
        v2f T01 = S01 + S45;          // (t0,t1) = (s0+s4, s1+s5)
        v2f T23 = S23 + S67;          // (t2,t3)
        float u0  = T01.x + T01.y;    // t0+t1   (np tree, exact order)
        float u1  = T23.x + T23.y;    // t2+t3
        float dot = u0 + u1;
        if (dot > best) { best = dot; bestk = k; }  // strict >: first max = np.argmax
    }

    bestk8[(size_t)b * M_SZ + m] = (unsigned char)bestk;
}

// ---------------- K2: fill-shaped writer (unchanged from R4) ----------------
// 4096 blocks x 256 threads; block owns b rows [4*blk, 4*blk+4) = 256 KB slab.
__global__ __launch_bounds__(256) void pq_fill(
    const float* __restrict__ C,
    const unsigned char* __restrict__ bestk8,  // [B][M]
    float* __restrict__ xhat,
    float* __restrict__ codes)
{
    const int t    = threadIdx.x;
    const int b0   = blockIdx.x << 2;
    const int w    = t >> 6;         // wave 0..3
    const int lane = t & 63;

    __shared__ unsigned char lbk[4 * M_SZ];

    lbk[t] = bestk8[(size_t)b0 * M_SZ + t];

    // xhat: wave w -> row b0+w, lane -> m. Coalesced 2KB/wave.
    {
        const int b  = b0 + w;
        const int kb = (int)bestk8[(size_t)b * M_SZ + lane];
        const float* cw = C + ((size_t)lane * K_SZ + kb) * D_SZ;
        const float4 h0 = ((const float4*)cw)[0];
        const float4 h1 = ((const float4*)cw)[1];
        float* xh = xhat + (size_t)b * FEAT + lane * D_SZ;
        ((float4*)xh)[0] = h0;
        ((float4*)xh)[1] = h1;
    }

    __syncthreads();

    // codes slab: 64 float4 stores/thread, one-hot folded in-stream.
    const int lane4 = lane << 2;
    float4* const slab = (float4*)(codes + (size_t)b0 * (M_SZ * K_SZ));

#pragma unroll 4
    for (int j = 0; j < 64; ++j) {
        const int r  = j >> 4;
        const int mj = (w + 4 * j) & 63;
        const int kk = (int)lbk[(r << 6) | mj];   // LDS broadcast (uniform)
        float4 v;
        v.x = (kk == lane4 + 0) ? 1.0f : 0.0f;
        v.y = (kk == lane4 + 1) ? 1.0f : 0.0f;
        v.z = (kk == lane4 + 2) ? 1.0f : 0.0f;
        v.w = (kk == lane4 + 3) ? 1.0f : 0.0f;
        slab[t + 256 * j] = v;
    }
}

extern "C" void kernel_launch(void* const* d_in, const int* in_sizes, int n_in,
                              void* d_out, int out_size, void* d_ws, size_t ws_size,
                              hipStream_t stream)
{
    const float* x = (const float*)d_in[0];
    const float* C = (const float*)d_in[1];
    float* xhat  = (float*)d_out;                           // (B, 512)
    float* codes = (float*)d_out + (size_t)B_SZ * FEAT;     // (B, 64, 256)
    unsigned char* bestk8 = (unsigned char*)d_ws;           // [B][M] u8 = 1 MB

    // Bisection: 3x K1' + 2x K2 (idempotent; same work every call).
    hipLaunchKernelGGL(pq_argmax, dim3(4096), dim3(256), 0, stream, x, C, bestk8);
    hipLaunchKernelGGL(pq_argmax, dim3(4096), dim3(256), 0, stream, x, C, bestk8);
    hipLaunchKernelGGL(pq_argmax, dim3(4096), dim3(256), 0, stream, x, C, bestk8);
    hipLaunchKernelGGL(pq_fill,   dim3(4096), dim3(256), 0, stream, C, bestk8, xhat, codes);
    hipLaunchKernelGGL(pq_fill,   dim3(4096), dim3(256), 0, stream, C, bestk8, xhat, codes);
}

// Round 6
// 1335.896 us; speedup vs baseline: 1.2340x; 1.2340x over previous
//
#include <hip/hip_runtime.h>
#include <math.h>

// PQLayer forward, MI355X — R6.
//   x: (B,512) fp32   C: (64,256,8) fp32
//   out0 x_hat (B,512) = C[m,k*,:]   out1 codes (B,64,256) = one_hot(k*)
//
// Measurement model: dur_us = F (harness poison/restore tax, 707-890us) +
// kernel time. Bisection R5: K2 at HBM floor (~180-200us); K1 130-180us vs
// ~45us VALU floor -> issue/latency-bound.
//
// R6 change (K1 ONLY; K2 bit-frozen from R4):
//   thread = (b, m-pair): two independent argmax chains -> 2x ILP, 8192 waves
//   = 8/SIMD exactly (no 2:1 oversubscription), one contiguous 64 B x-load,
//   wave-uniform C s_loads (64 B/k), u16 packed bestk store.
//   Packed v2f np-tree kept (R5: absmax 0.0 proves bit-exactness).

#define B_SZ   16384
#define FEAT   512
#define M_SZ   64
#define K_SZ   256
#define D_SZ   8

typedef float v2f __attribute__((ext_vector_type(2)));

// ---------------- K1: dual-chain packed argmax ----------------
// 2048 blocks x 256 threads = 8192 waves. wave = (chunk, m-pair); lane = b.
__global__ __launch_bounds__(256) void pq_argmax(
    const float* __restrict__ x,
    const float* __restrict__ C,
    unsigned char* __restrict__ bestk8)   // [B][M]
{
#pragma clang fp contract(off)   // np einsum: separate product roundings, no FMA

    const int w     = threadIdx.x >> 6;      // wave-in-block 0..3
    const int lane  = threadIdx.x & 63;
    const int chunk = blockIdx.x >> 3;       // 0..255 (64 b's each)
    const int mpg   = blockIdx.x & 7;        // m-pair group 0..7
    const int mp    = (mpg << 2) | w;        // m-pair 0..31 (block-uniform per wave)
    const int m0    = mp << 1;               // even m; m1 = m0+1
    const int b     = (chunk << 6) | lane;

    // x[b, 8*m0 .. 8*m0+16): 64 B contiguous per thread
    const float4* xp = (const float4*)(x + (size_t)b * FEAT + m0 * D_SZ);
    const float4 xA = xp[0], xB = xp[1];     // chain 0 (m0)
    const float4 xC = xp[2], xD = xp[3];     // chain 1 (m1)
    const v2f a01 = {xA.x, xA.y}, a23 = {xA.z, xA.w};
    const v2f a45 = {xB.x, xB.y}, a67 = {xB.z, xB.w};
    const v2f c01 = {xC.x, xC.y}, c23 = {xC.z, xC.w};
    const v2f c45 = {xD.x, xD.y}, c67 = {xD.z, xD.w};

    const float* __restrict__ Cm0 = C + (size_t)m0 * (K_SZ * D_SZ);
    const float* __restrict__ Cm1 = Cm0 + (K_SZ * D_SZ);

    float best0 = -INFINITY, best1 = -INFINITY;
    int   bk0 = 0, bk1 = 0;

#pragma unroll 4
    for (int k = 0; k < K_SZ; ++k) {
        const v2f* cr0 = (const v2f*)(Cm0 + k * D_SZ);  // uniform -> s_load
        const v2f* cr1 = (const v2f*)(Cm1 + k * D_SZ);

        // chain 0 — np SSE pairwise tree, each half rounds separately
        v2f S0 = a01 * cr0[0];
        v2f S1 = a23 * cr0[1];
        v2f S2 = a45 * cr0[2];
        v2f S3 = a67 * cr0[3];
        // chain 1
        v2f T0 = c01 * cr1[0];
        v2f T1 = c23 * cr1[1];
        v2f T2 = c45 * cr1[2];
        v2f T3 = c67 * cr1[3];

        v2f SP = S0 + S2;            // (s0+s4, s1+s5)
        v2f SQ = S1 + S3;            // (s2+s6, s3+s7)
        v2f TP = T0 + T2;
        v2f TQ = T1 + T3;

        float d0 = (SP.x + SP.y) + (SQ.x + SQ.y);   // np tree, exact order
        float d1 = (TP.x + TP.y) + (TQ.x + TQ.y);

        // strict >: first max = np.argmax
        bool g0 = d0 > best0;
        bk0   = g0 ? k  : bk0;
        best0 = g0 ? d0 : best0;
        bool g1 = d1 > best1;
        bk1   = g1 ? k  : bk1;
        best1 = g1 ? d1 : best1;
    }

    // adjacent (m0, m0+1) bytes -> one aligned u16 store
    *(unsigned short*)(bestk8 + (size_t)b * M_SZ + m0) =
        (unsigned short)(bk0 | (bk1 << 8));
}

// ---------------- K2: fill-shaped writer (bit-frozen from R4) ----------------
// 4096 blocks x 256 threads; block owns b rows [4*blk, 4*blk+4) = 256 KB slab.
__global__ __launch_bounds__(256) void pq_fill(
    const float* __restrict__ C,
    const unsigned char* __restrict__ bestk8,  // [B][M]
    float* __restrict__ xhat,
    float* __restrict__ codes)
{
    const int t    = threadIdx.x;
    const int b0   = blockIdx.x << 2;
    const int w    = t >> 6;         // wave 0..3
    const int lane = t & 63;

    __shared__ unsigned char lbk[4 * M_SZ];

    lbk[t] = bestk8[(size_t)b0 * M_SZ + t];

    // xhat: wave w -> row b0+w, lane -> m. Coalesced 2KB/wave.
    {
        const int b  = b0 + w;
        const int kb = (int)bestk8[(size_t)b * M_SZ + lane];
        const float* cw = C + ((size_t)lane * K_SZ + kb) * D_SZ;
        const float4 h0 = ((const float4*)cw)[0];
        const float4 h1 = ((const float4*)cw)[1];
        float* xh = xhat + (size_t)b * FEAT + lane * D_SZ;
        ((float4*)xh)[0] = h0;
        ((float4*)xh)[1] = h1;
    }

    __syncthreads();

    // codes slab: 64 float4 stores/thread, one-hot folded in-stream.
    const int lane4 = lane << 2;
    float4* const slab = (float4*)(codes + (size_t)b0 * (M_SZ * K_SZ));

#pragma unroll 4
    for (int j = 0; j < 64; ++j) {
        const int r  = j >> 4;
        const int mj = (w + 4 * j) & 63;
        const int kk = (int)lbk[(r << 6) | mj];   // LDS broadcast (uniform)
        float4 v;
        v.x = (kk == lane4 + 0) ? 1.0f : 0.0f;
        v.y = (kk == lane4 + 1) ? 1.0f : 0.0f;
        v.z = (kk == lane4 + 2) ? 1.0f : 0.0f;
        v.w = (kk == lane4 + 3) ? 1.0f : 0.0f;
        slab[t + 256 * j] = v;
    }
}

extern "C" void kernel_launch(void* const* d_in, const int* in_sizes, int n_in,
                              void* d_out, int out_size, void* d_ws, size_t ws_size,
                              hipStream_t stream)
{
    const float* x = (const float*)d_in[0];
    const float* C = (const float*)d_in[1];
    float* xhat  = (float*)d_out;                           // (B, 512)
    float* codes = (float*)d_out + (size_t)B_SZ * FEAT;     // (B, 64, 256)
    unsigned char* bestk8 = (unsigned char*)d_ws;           // [B][M] u8 = 1 MB

    hipLaunchKernelGGL(pq_argmax, dim3(2048), dim3(256), 0, stream, x, C, bestk8);
    hipLaunchKernelGGL(pq_fill,   dim3(4096), dim3(256), 0, stream, C, bestk8, xhat, codes);
}

// Round 7
// 1203.120 us; speedup vs baseline: 1.3702x; 1.1104x over previous
//
#include <hip/hip_runtime.h>
#include <math.h>

// PQLayer forward, MI355X — R7.
//   x: (B,512) fp32   C: (64,256,8) fp32
//   out0 x_hat (B,512) = C[m,k*,:]   out1 codes (B,64,256) = one_hot(k*)
//
// Model (R4/R5/R6 algebra): dur = F(~707us harness tax) + t1 + t2.
//   t1 scalar ~300, packed ~180; t2 ~200 = HBM floor. R6 dual-chain broke
//   block-uniform m -> L1 thrash -> t1 ~430 (40ms under profiling). Reverted.
//
// R7 (K1 only; K2 bit-frozen from R4): R5 mapping (m block-uniform, C[m] 8KB
// L1-resident) + C loads widened to 2x float4/k (VMEM instrs halved 4->2).
// v4f packed tree is bit-exact to np: P=xa*ca, Q=xb*cb round per-half like
// scalar; T=P+Q=(t0..t3); dot=(T.x+T.y)+(T.z+T.w) in np's exact order.

#define B_SZ   16384
#define FEAT   512
#define M_SZ   64
#define K_SZ   256
#define D_SZ   8

typedef float v4f __attribute__((ext_vector_type(4)));

// ---------------- K1: packed argmax, wide C loads ----------------
// 4096 blocks x 256 threads; block = (m, chunk of 256 b); thread = one b.
__global__ __launch_bounds__(256) void pq_argmax(
    const float* __restrict__ x,
    const float* __restrict__ C,
    unsigned char* __restrict__ bestk8)   // [B][M]
{
#pragma clang fp contract(off)   // np einsum: separate product roundings, no FMA

    const int m     = blockIdx.x & (M_SZ - 1);   // block-uniform -> C[m] L1-hot
    const int chunk = blockIdx.x >> 6;
    const int b     = (chunk << 8) | threadIdx.x;

    const float* xp = x + (size_t)b * FEAT + m * D_SZ;
    const v4f xa = ((const v4f*)xp)[0];   // (x0..x3)
    const v4f xb = ((const v4f*)xp)[1];   // (x4..x7)

    const float* __restrict__ Cm = C + (size_t)m * (K_SZ * D_SZ);

    float best  = -INFINITY;
    int   bestk = 0;

#pragma unroll 8
    for (int k = 0; k < K_SZ; ++k) {
        const v4f* cr = (const v4f*)(Cm + k * D_SZ);  // 32B-aligned, uniform
        const v4f ca = cr[0];             // one dwordx4 load
        const v4f cb = cr[1];             // one dwordx4 load
        v4f P = xa * ca;                  // (s0..s3)  v_pk_mul_f32 x2
        v4f Q = xb * cb;                  // (s4..s7)
        v4f T = P + Q;                    // (t0..t3)  v_pk_add_f32 x2
        float dot = (T.x + T.y) + (T.z + T.w);   // np tree, exact order
        if (dot > best) { best = dot; bestk = k; }  // strict >: first max
    }

    bestk8[(size_t)b * M_SZ + m] = (unsigned char)bestk;  // L2 merges bytes
}

// ---------------- K2: fill-shaped writer (bit-frozen from R4) ----------------
// 4096 blocks x 256 threads; block owns b rows [4*blk, 4*blk+4) = 256 KB slab.
__global__ __launch_bounds__(256) void pq_fill(
    const float* __restrict__ C,
    const unsigned char* __restrict__ bestk8,  // [B][M]
    float* __restrict__ xhat,
    float* __restrict__ codes)
{
    const int t    = threadIdx.x;
    const int b0   = blockIdx.x << 2;
    const int w    = t >> 6;         // wave 0..3
    const int lane = t & 63;

    __shared__ unsigned char lbk[4 * M_SZ];

    lbk[t] = bestk8[(size_t)b0 * M_SZ + t];

    // xhat: wave w -> row b0+w, lane -> m. Coalesced 2KB/wave.
    {
        const int b  = b0 + w;
        const int kb = (int)bestk8[(size_t)b * M_SZ + lane];
        const float* cw = C + ((size_t)lane * K_SZ + kb) * D_SZ;
        const float4 h0 = ((const float4*)cw)[0];
        const float4 h1 = ((const float4*)cw)[1];
        float* xh = xhat + (size_t)b * FEAT + lane * D_SZ;
        ((float4*)xh)[0] = h0;
        ((float4*)xh)[1] = h1;
    }

    __syncthreads();

    // codes slab: 64 float4 stores/thread, one-hot folded in-stream.
    const int lane4 = lane << 2;
    float4* const slab = (float4*)(codes + (size_t)b0 * (M_SZ * K_SZ));

#pragma unroll 4
    for (int j = 0; j < 64; ++j) {
        const int r  = j >> 4;
        const int mj = (w + 4 * j) & 63;
        const int kk = (int)lbk[(r << 6) | mj];   // LDS broadcast (uniform)
        float4 v;
        v.x = (kk == lane4 + 0) ? 1.0f : 0.0f;
        v.y = (kk == lane4 + 1) ? 1.0f : 0.0f;
        v.z = (kk == lane4 + 2) ? 1.0f : 0.0f;
        v.w = (kk == lane4 + 3) ? 1.0f : 0.0f;
        slab[t + 256 * j] = v;
    }
}

extern "C" void kernel_launch(void* const* d_in, const int* in_sizes, int n_in,
                              void* d_out, int out_size, void* d_ws, size_t ws_size,
                              hipStream_t stream)
{
    const float* x = (const float*)d_in[0];
    const float* C = (const float*)d_in[1];
    float* xhat  = (float*)d_out;                           // (B, 512)
    float* codes = (float*)d_out + (size_t)B_SZ * FEAT;     // (B, 64, 256)
    unsigned char* bestk8 = (unsigned char*)d_ws;           // [B][M] u8 = 1 MB

    hipLaunchKernelGGL(pq_argmax, dim3(4096), dim3(256), 0, stream, x, C, bestk8);
    hipLaunchKernelGGL(pq_fill,   dim3(4096), dim3(256), 0, stream, C, bestk8, xhat, codes);
}